// Round 1
// baseline (211.776 us; speedup 1.0000x reference)
//
#include <hip/hip_runtime.h>
#include <math.h>

#define N 1024
#define KD 5

// ---------- reduction helpers ----------
__device__ __forceinline__ float wred_sum(float v){
#pragma unroll
  for (int off = 32; off > 0; off >>= 1) v += __shfl_down(v, off);
  return v;
}
__device__ __forceinline__ float wred_max(float v){
#pragma unroll
  for (int off = 32; off > 0; off >>= 1) v = fmaxf(v, __shfl_down(v, off));
  return v;
}
// 256-thread block reductions; broadcast result to all threads.
__device__ __forceinline__ float block_sum(float v, volatile float* s4){
  float w = wred_sum(v);
  if ((threadIdx.x & 63) == 0) s4[threadIdx.x >> 6] = w;
  __syncthreads();
  float r = (s4[0] + s4[1]) + (s4[2] + s4[3]);
  __syncthreads();
  return r;
}
__device__ __forceinline__ float block_max(float v, volatile float* s4){
  float w = wred_max(v);
  if ((threadIdx.x & 63) == 0) s4[threadIdx.x >> 6] = w;
  __syncthreads();
  float r = fmaxf(fmaxf(s4[0], s4[1]), fmaxf(s4[2], s4[3]));
  __syncthreads();
  return r;
}

// scalar-input 2-layer MLP, weights in LDS (broadcast reads)
__device__ __forceinline__ float mlp_eval(float x, const float* __restrict__ w1,
                                          const float* __restrict__ b1,
                                          const float* __restrict__ w2, float b2){
  float acc = b2;
#pragma unroll
  for (int k = 0; k < 64; ++k){
    float h = fmaxf(fmaf(x, w1[k], b1[k]), 0.0f);
    acc = fmaf(h, w2[k], acc);
  }
  return acc;
}

// ---------- init: degrees (distinct-count of adj rows) + ttheta ----------
__global__ __launch_bounds__(1024) void k_init(const int* __restrict__ adj1,
                                               const int* __restrict__ adj2,
                                               float* __restrict__ d1,
                                               float* __restrict__ d2,
                                               float* __restrict__ ttv){
  int tid = threadIdx.x;
  int v[KD];
#pragma unroll
  for (int r = 0; r < KD; ++r) v[r] = adj1[tid * KD + r];
  int c1 = 0;
#pragma unroll
  for (int r = 0; r < KD; ++r){
    bool dup = false;
#pragma unroll
    for (int s = 0; s < r; ++s) dup = dup || (v[s] == v[r]);
    c1 += dup ? 0 : 1;
  }
  d1[tid] = (float)c1;
#pragma unroll
  for (int r = 0; r < KD; ++r) v[r] = adj2[tid * KD + r];
  int c2 = 0;
#pragma unroll
  for (int r = 0; r < KD; ++r){
    bool dup = false;
#pragma unroll
    for (int s = 0; s < r; ++s) dup = dup || (v[s] == v[r]);
    c2 += dup ? 0 : 1;
  }
  d2[tid] = (float)c2;

  __shared__ float sred[16];
  float s = wred_sum((float)c1);
  if ((tid & 63) == 0) sred[tid >> 6] = s;
  __syncthreads();
  if (tid == 0){
    float tot = 0.0f;
    for (int i = 0; i < 16; ++i) tot += sred[i];
    ttv[0] = tot / (float)N;   // ttheta (exact: integer sum < 2^24)
  }
}

// ---------- layer-0 row kernel: S0 -> mlp0 -> t0 = y - rowmax, R = 1/rowsumexp ----------
__global__ __launch_bounds__(256) void k_row0(const float* __restrict__ d1,
                                              const float* __restrict__ d2,
                                              const float* __restrict__ ttv,
                                              const float* __restrict__ w1g,
                                              const float* __restrict__ b1g,
                                              const float* __restrict__ w2g,
                                              const float* __restrict__ b2g,
                                              float* __restrict__ t0,
                                              float* __restrict__ R){
  __shared__ float sW[193];
  __shared__ float s4[4];
  int a = blockIdx.x, tid = threadIdx.x;
  if (tid < 64){ sW[tid] = w1g[tid]; sW[64+tid] = b1g[tid]; sW[128+tid] = w2g[tid]; }
  if (tid == 0) sW[192] = b2g[0];
  __syncthreads();
  float da = d1[a], tt = ttv[0];
  float y[4];
#pragma unroll
  for (int jc = 0; jc < 4; ++jc){
    int j = jc * 256 + tid;
    float S = -fabsf(da - d2[j]);
    y[jc] = mlp_eval(S / tt, sW, sW + 64, sW + 128, sW[192]);
  }
  float rm = block_max(fmaxf(fmaxf(y[0], y[1]), fmaxf(y[2], y[3])), s4);
  float acc = 0.0f;
#pragma unroll
  for (int jc = 0; jc < 4; ++jc){
    int j = jc * 256 + tid;
    float tv = y[jc] - rm;
    t0[(size_t)a * N + j] = tv;
    acc += expf(tv);
  }
  float tot = block_sum(acc, s4);
  if (tid == 0) R[a] = 1.0f / tot;
}

// ---------- sinkhorn column pass: Csum[j] += sum_i exp(t[i,j]) * R[i]  (split-K atomics) ----------
__global__ __launch_bounds__(256) void k_colpass(const float* __restrict__ t,
                                                 const float* __restrict__ R,
                                                 float* __restrict__ Csum){
  int j  = blockIdx.x * 256 + threadIdx.x;
  int i0 = blockIdx.y * 32;
  float acc = 0.0f;
#pragma unroll 8
  for (int ii = 0; ii < 32; ++ii){
    int i = i0 + ii;
    acc = fmaf(expf(t[(size_t)i * N + j]), R[i], acc);
  }
  atomicAdd(&Csum[j], acc);
}

// ---------- sinkhorn row pass: R[i] = 1 / sum_j exp(t[i,j]) / Csum[j] ----------
__global__ __launch_bounds__(256) void k_rowpass(const float* __restrict__ t,
                                                 const float* __restrict__ Csum,
                                                 float* __restrict__ R){
  __shared__ float s4[4];
  int a = blockIdx.x, tid = threadIdx.x;
  float acc = 0.0f;
#pragma unroll
  for (int jc = 0; jc < 4; ++jc){
    int j = jc * 256 + tid;
    acc += expf(t[(size_t)a * N + j]) / Csum[j];
  }
  float tot = block_sum(acc, s4);
  if (tid == 0) R[a] = 1.0f / tot;
}

// ---------- A[a] = 5*log(1536) + sum_r log R[adj1[a,r]];  B[b] = -sum_c log Csum[adj2[b,c]] ----------
__global__ __launch_bounds__(256) void k_ab(const int* __restrict__ adj1,
                                            const int* __restrict__ adj2,
                                            const float* __restrict__ R,
                                            const float* __restrict__ Cs,
                                            float* __restrict__ Av,
                                            float* __restrict__ Bv){
  int tid = blockIdx.x * 256 + threadIdx.x;
  if (tid < N){
    float s = 5.0f * logf(1536.0f);
#pragma unroll
    for (int r = 0; r < KD; ++r) s += logf(R[adj1[tid * KD + r]]);
    Av[tid] = s;
  } else if (tid < 2 * N){
    int b = tid - N;
    float s = 0.0f;
#pragma unroll
    for (int c = 0; c < KD; ++c) s -= logf(Cs[adj2[b * KD + c]]);
    Bv[b] = s;
  }
}

// ---------- X1 kernel: block per row a. Stage 5 t-rows in LDS, DP assignment-max,
//            fuse next-layer MLP + rowmax (+rowsum / final-softmax row stats) ----------
__global__ __launch_bounds__(256) void k_x1(const float* __restrict__ t,
                                            const int* __restrict__ adj1,
                                            const int* __restrict__ adj2,
                                            const float* __restrict__ Av,
                                            const float* __restrict__ Bv,
                                            const float* __restrict__ w1g,
                                            const float* __restrict__ b1g,
                                            const float* __restrict__ w2g,
                                            const float* __restrict__ b2g,
                                            const float* __restrict__ ttv,
                                            int isFinal,
                                            float* __restrict__ tnext,
                                            float* __restrict__ Rout,
                                            float* __restrict__ rowmaxF,
                                            float* __restrict__ rowsumF){
  __shared__ float rows[KD][N];
  __shared__ float sW[193];
  __shared__ float s4[4];
  int a = blockIdx.x, tid = threadIdx.x;
#pragma unroll
  for (int r = 0; r < KD; ++r){
    int src = adj1[a * KD + r];
    float4 vv = ((const float4*)(t + (size_t)src * N))[tid];
    ((float4*)(&rows[r][0]))[tid] = vv;
  }
  if (tid < 64){ sW[tid] = w1g[tid]; sW[64+tid] = b1g[tid]; sW[128+tid] = w2g[tid]; }
  if (tid == 0) sW[192] = b2g[0];
  __syncthreads();
  float Aa = Av[a];
  float tt = ttv[0];
  float y[4];
#pragma unroll
  for (int jc = 0; jc < 4; ++jc){
    int b = jc * 256 + tid;
    int idx[KD];
#pragma unroll
    for (int c = 0; c < KD; ++c) idx[c] = adj2[b * KD + c];
    float t5[KD][KD];
#pragma unroll
    for (int r = 0; r < KD; ++r)
#pragma unroll
      for (int c = 0; c < KD; ++c) t5[r][c] = rows[r][idx[c]];
    // subset-DP assignment max: f[mask] = best assignment of rows 0..popc-1 to cols in mask
    float f[32];
    f[0] = 0.0f;
#pragma unroll
    for (int mask = 1; mask < 32; ++mask){
      int rr = __popc(mask) - 1;           // constant-folds after unroll
      float best = -3.0e38f;
#pragma unroll
      for (int c = 0; c < KD; ++c)
        if (mask & (1 << c)) best = fmaxf(best, f[mask ^ (1 << c)] + t5[rr][c]);
      f[mask] = best;
    }
    float X1v = Aa + Bv[b] + f[31];
    float x = isFinal ? X1v : (X1v / tt);
    y[jc] = mlp_eval(x, sW, sW + 64, sW + 128, sW[192]);
  }
  float rm = block_max(fmaxf(fmaxf(y[0], y[1]), fmaxf(y[2], y[3])), s4);
  float acc = 0.0f;
  if (!isFinal){
#pragma unroll
    for (int jc = 0; jc < 4; ++jc){
      int b = jc * 256 + tid;
      float tv = y[jc] - rm;
      tnext[(size_t)a * N + b] = tv;
      acc += expf(tv);
    }
    float tot = block_sum(acc, s4);
    if (tid == 0) Rout[a] = 1.0f / tot;
  } else {
#pragma unroll
    for (int jc = 0; jc < 4; ++jc){
      int b = jc * 256 + tid;
      tnext[(size_t)a * N + b] = y[jc];    // store unshifted y_final
      acc += expf(y[jc] - rm);
    }
    float tot = block_sum(acc, s4);
    if (tid == 0){ rowmaxF[a] = rm; rowsumF[a] = tot; }
  }
}

// ---------- final column softmax denominator (unshifted; |y| is O(10)) ----------
__global__ __launch_bounds__(256) void k_colpassF(const float* __restrict__ y,
                                                  float* __restrict__ cs){
  int j  = blockIdx.x * 256 + threadIdx.x;
  int i0 = blockIdx.y * 32;
  float acc = 0.0f;
#pragma unroll 8
  for (int ii = 0; ii < 32; ++ii) acc += expf(y[(size_t)(i0 + ii) * N + j]);
  atomicAdd(&cs[j], acc);
}

// ---------- combine: out = 0.5*(row_softmax + col_softmax), in place ----------
__global__ __launch_bounds__(256) void k_combine(const float* __restrict__ y,
                                                 const float* __restrict__ rmF,
                                                 const float* __restrict__ rsF,
                                                 const float* __restrict__ cs,
                                                 float* __restrict__ out){
  int a = blockIdx.x, tid = threadIdx.x;
  float rm = rmF[a];
  float rsinv = 1.0f / rsF[a];
#pragma unroll
  for (int jc = 0; jc < 4; ++jc){
    int j = jc * 256 + tid;
    float yv = y[(size_t)a * N + j];
    float s1 = expf(yv - rm) * rsinv;
    float s2 = expf(yv) / cs[j];
    out[(size_t)a * N + j] = 0.5f * (s1 + s2);
  }
}

extern "C" void kernel_launch(void* const* d_in, const int* in_sizes, int n_in,
                              void* d_out, int out_size, void* d_ws, size_t ws_size,
                              hipStream_t stream){
  (void)in_sizes; (void)n_in; (void)out_size; (void)ws_size;
  // inputs: 0 G1 (unused), 1 G2 (unused), 2 adj1, 3 adj2,
  //         4 ro_W1, 5 ro_b1, 6 ro_W2, 7 ro_b2, 8 fin_W1, 9 fin_b1, 10 fin_W2, 11 fin_b2
  const int*   adj1 = (const int*)d_in[2];
  const int*   adj2 = (const int*)d_in[3];
  const float* roW1 = (const float*)d_in[4];
  const float* roB1 = (const float*)d_in[5];
  const float* roW2 = (const float*)d_in[6];
  const float* roB2 = (const float*)d_in[7];
  const float* fW1  = (const float*)d_in[8];
  const float* fB1  = (const float*)d_in[9];
  const float* fW2  = (const float*)d_in[10];
  const float* fB2  = (const float*)d_in[11];
  float* out = (float*)d_out;

  // ws layout: one N*N matrix + small vectors (~4.3 MB total)
  float* bufA  = (float*)d_ws;
  float* R     = bufA + (size_t)N * N;
  float* Av    = R + N;
  float* Bv    = Av + N;
  float* d1    = Bv + N;
  float* d2    = d1 + N;
  float* ttv   = d2 + N;        // 8 floats
  float* rmF   = ttv + 8;
  float* rsF   = rmF + N;
  float* csums = rsF + N;       // 10*N atomic accumulators

  hipMemsetAsync(csums, 0, 10 * N * sizeof(float), stream);
  k_init<<<1, 1024, 0, stream>>>(adj1, adj2, d1, d2, ttv);
  k_row0<<<N, 256, 0, stream>>>(d1, d2, ttv, roW1, roB1, roW2, roB2, bufA, R);

  for (int li = 0; li < 3; ++li){
    const float* tcur = (li == 1) ? out : bufA;   // ping-pong: t0=bufA, t1=out, t2=bufA
    float* tnext      = (li == 1) ? bufA : out;
    float* c0 = csums + (size_t)(3 * li + 0) * N;
    float* c1 = csums + (size_t)(3 * li + 1) * N;
    float* c2 = csums + (size_t)(3 * li + 2) * N;
    // sinkhorn(5): init row softmax already folded into t/R; then col,row,col,row,col
    k_colpass<<<dim3(4, 32), 256, 0, stream>>>(tcur, R, c0);
    k_rowpass<<<N, 256, 0, stream>>>(tcur, c0, R);
    k_colpass<<<dim3(4, 32), 256, 0, stream>>>(tcur, R, c1);
    k_rowpass<<<N, 256, 0, stream>>>(tcur, c1, R);
    k_colpass<<<dim3(4, 32), 256, 0, stream>>>(tcur, R, c2);
    k_ab<<<8, 256, 0, stream>>>(adj1, adj2, R, c2, Av, Bv);
    int isFinal = (li == 2);
    const float* w1 = isFinal ? fW1 : roW1 + (li + 1) * 64;
    const float* b1 = isFinal ? fB1 : roB1 + (li + 1) * 64;
    const float* w2 = isFinal ? fW2 : roW2 + (li + 1) * 64;
    const float* b2 = isFinal ? fB2 : roB2 + (li + 1);
    k_x1<<<N, 256, 0, stream>>>(tcur, adj1, adj2, Av, Bv, w1, b1, w2, b2, ttv,
                                isFinal, tnext, R, rmF, rsF);
  }
  float* cF = csums + (size_t)9 * N;
  k_colpassF<<<dim3(4, 32), 256, 0, stream>>>(out, cF);
  k_combine<<<N, 256, 0, stream>>>(out, rmF, rsF, cF, out);
}